// Round 3
// baseline (190.686 us; speedup 1.0000x reference)
//
#include <hip/hip_runtime.h>
#include <cstdint>
#include <cstddef>

#define NUM_HEADS 16
#define HEAD_DIM  64
#define WINDOW    512
#define D_MODEL   1024
#define BATCH     2
#define SEQ       2048
#define MTOT      (BATCH*SEQ)   // 4096
#define NQKV      (3*D_MODEL)   // 3072

typedef short bf16x8 __attribute__((ext_vector_type(8)));
typedef float f32x4  __attribute__((ext_vector_type(4)));

__device__ __forceinline__ f32x4 mfma16(bf16x8 a, bf16x8 b, f32x4 c) {
  return __builtin_amdgcn_mfma_f32_16x16x32_bf16(a, b, c, 0, 0, 0);
}

__device__ __forceinline__ unsigned short f2bf(float f) {
  unsigned int u = __float_as_uint(f);
  u += 0x7fffu + ((u >> 16) & 1u);
  return (unsigned short)(u >> 16);
}
__device__ __forceinline__ float bf2f(unsigned short b) {
  return __uint_as_float(((unsigned int)b) << 16);
}

// async global->LDS, 16B/lane; LDS dest = wave-uniform base + lane*16 (m104).
__device__ __forceinline__ void gld16(const unsigned short* g, unsigned short* l) {
  __builtin_amdgcn_global_load_lds(
      (const __attribute__((address_space(1))) unsigned int*)g,
      (__attribute__((address_space(3))) unsigned int*)l, 16, 0, 0);
}

// ---------------- elementwise fp32 -> bf16 ----------------
__global__ __launch_bounds__(256) void cvt_bf16_kernel(const float* __restrict__ in,
                                                       unsigned short* __restrict__ out) {
  int i = (blockIdx.x * 256 + threadIdx.x) * 4;
  float4 v = *(const float4*)(in + i);
  ushort4 o;
  o.x = f2bf(v.x); o.y = f2bf(v.y); o.z = f2bf(v.z); o.w = f2bf(v.w);
  *(ushort4*)(out + i) = o;
}

// ---------------- transpose + convert: fp32 (R,C) -> bf16 (C,R) ----------------
__global__ __launch_bounds__(256) void transpose_cvt_kernel(const float* __restrict__ in,
                                                            unsigned short* __restrict__ out,
                                                            int R, int C) {
  __shared__ float tile[32][33];
  int tx = threadIdx.x, ty = threadIdx.y;          // (32, 8)
  int c0 = blockIdx.x * 32, r0 = blockIdx.y * 32;
#pragma unroll
  for (int i = 0; i < 32; i += 8)
    tile[ty + i][tx] = in[(size_t)(r0 + ty + i) * C + c0 + tx];
  __syncthreads();
#pragma unroll
  for (int i = 0; i < 32; i += 8)
    out[(size_t)(c0 + ty + i) * R + r0 + tx] = f2bf(tile[tx][ty + i]);
}

// ---------------- m97-style 128x128 bf16 GEMM mainloop, XOR-swizzled LDS -------
// A row-major (M,K), Bt row-major (N,K). SWAP=false: acc[i][j] = C tile
// (row=m, col=n). SWAP=true: acc[i][j] = C^T tile (row=n, col=m).
template<bool SWAP>
__device__ __forceinline__ void gemm_mainloop(const unsigned short* __restrict__ A,
                                              const unsigned short* __restrict__ Bt,
                                              int K, int m0, int n0,
                                              unsigned short* sA, unsigned short* sB,
                                              f32x4 (&acc)[4][4]) {
  const int t = threadIdx.x;
  const int lane = t & 63, wave = t >> 6;
  const int wm = wave >> 1, wn = wave & 1;
  const int lhi = lane >> 4, llo = lane & 15;
  f32x4 zero = {0.f, 0.f, 0.f, 0.f};
#pragma unroll
  for (int i = 0; i < 4; ++i)
#pragma unroll
    for (int j = 0; j < 4; ++j) acc[i][j] = zero;

  const int cswz = (((t & 3) ^ ((t >> 3) & 3)) << 3);   // swizzled k-chunk for staging
  const unsigned short* gA = A  + (size_t)(m0 + (t >> 2)) * K + cswz;
  const unsigned short* gB = Bt + (size_t)(n0 + (t >> 2)) * K + cswz;
  const size_t rowskip = (size_t)64 * K;
  unsigned short* lA = sA + t * 8;
  unsigned short* lB = sB + t * 8;
  const int rsw = (lhi ^ ((llo >> 1) & 3)) * 8;          // swizzled chunk for frag reads
  const unsigned short* rA = sA + (wm * 64 + llo) * 32 + rsw;
  const unsigned short* rB = sB + (wn * 64 + llo) * 32 + rsw;

  for (int k0 = 0; k0 < K; k0 += 32) {
    gld16(gA, lA); gld16(gA + rowskip, lA + 2048);
    gld16(gB, lB); gld16(gB + rowskip, lB + 2048);
    gA += 32; gB += 32;
    __syncthreads();
    bf16x8 af[4], bfr[4];
#pragma unroll
    for (int i = 0; i < 4; ++i) af[i]  = *(const bf16x8*)(rA + i * 512);
#pragma unroll
    for (int i = 0; i < 4; ++i) bfr[i] = *(const bf16x8*)(rB + i * 512);
#pragma unroll
    for (int i = 0; i < 4; ++i)
#pragma unroll
      for (int j = 0; j < 4; ++j)
        acc[i][j] = SWAP ? mfma16(bfr[j], af[i], acc[i][j])
                         : mfma16(af[i], bfr[j], acc[i][j]);
    __syncthreads();
  }
}

// ---------------- QKV projection GEMM -----------------------------------------------------
// n0 < 2048 blocks: Q/K, normal orientation, coalesced (bh,s,d) stores.
// n0 >= 2048 blocks: V, transposed accumulator, DIRECT V^T (bh,d,s) stores (32B segments).
__global__ __launch_bounds__(256) void qkv_gemm_kernel(const unsigned short* __restrict__ Xb,
                                                       const unsigned short* __restrict__ Wt,
                                                       const float* __restrict__ bias,
                                                       unsigned short* __restrict__ Qw,
                                                       unsigned short* __restrict__ Kw,
                                                       unsigned short* __restrict__ Vtw) {
  __shared__ __align__(16) unsigned short sA[128 * 32];
  __shared__ __align__(16) unsigned short sB[128 * 32];
  f32x4 acc[4][4];
  const int m0 = blockIdx.y * 128, n0 = blockIdx.x * 128;
  const int t = threadIdx.x, lane = t & 63, wave = t >> 6;
  const int wm = wave >> 1, wn = wave & 1, lhi = lane >> 4, llo = lane & 15;

  if (n0 < 2048) {
    gemm_mainloop<false>(Xb, Wt, D_MODEL, m0, n0, sA, sB, acc);
#pragma unroll
    for (int ti = 0; ti < 4; ++ti) {
#pragma unroll
      for (int tj = 0; tj < 4; ++tj) {
        int n = n0 + wn * 64 + tj * 16 + llo;
        float bv = bias[n];
        int c = n >> 10, h = (n >> 6) & 15, d = n & 63;
#pragma unroll
        for (int r = 0; r < 4; ++r) {
          int m = m0 + wm * 64 + ti * 16 + lhi * 4 + r;
          int b = m >> 11, s = m & 2047;
          int bh = b * 16 + h;
          float v = acc[ti][tj][r] + bv;
          size_t idx = ((size_t)(bh * 2048 + s)) * 64 + d;
          if (c == 0) Qw[idx] = f2bf(v * 0.125f);
          else        Kw[idx] = f2bf(v);
        }
      }
    }
  } else {
    gemm_mainloop<true>(Xb, Wt, D_MODEL, m0, n0, sA, sB, acc);
#pragma unroll
    for (int ti = 0; ti < 4; ++ti) {
      int m = m0 + wm * 64 + ti * 16 + llo;   // s-dim (col of C^T)
      int b = m >> 11, s = m & 2047;
#pragma unroll
      for (int tj = 0; tj < 4; ++tj) {
        int nb = n0 + wn * 64 + tj * 16 + lhi * 4;   // d-base (row of C^T), 4-aligned
        float4 bv = *(const float4*)(bias + nb);
        int h = (nb >> 6) & 15, dbase = nb & 63;
        int bh = b * 16 + h;
        float bvr[4] = {bv.x, bv.y, bv.z, bv.w};
#pragma unroll
        for (int r = 0; r < 4; ++r)
          Vtw[(size_t)(bh * 64 + dbase + r) * 2048 + s] = f2bf(acc[ti][tj][r] + bvr[r]);
      }
    }
  }
}

// ---------------- flash sliding-window attention (S^T formulation, 128-q tiles) ----------
// grid (bh, q-rev). Per block: 128 queries = 2 q-sets of 64 (4 waves x 16 each),
// 64-key tiles, double-buffered K/V staging (1 barrier per k-tile), per-qset
// wave-uniform skip of fully-masked tiles.
__global__ __launch_bounds__(256) void attn_kernel(const unsigned short* __restrict__ Qw,
                                                   const unsigned short* __restrict__ Kw,
                                                   const unsigned short* __restrict__ Vtw,
                                                   unsigned short* __restrict__ AO) {
  __shared__ __align__(16) unsigned short sK[2][64 * 64];  // (key,d), XOR-swizzled chunks
  __shared__ __align__(16) unsigned short sV[2][64 * 64];  // (d,key), XOR-swizzled chunks
  __shared__ __align__(16) unsigned short sP[4][16 * 72];  // per-wave P, reused across qsets
  const int t = threadIdx.x, lane = t & 63, wave = t >> 6;
  const int lhi = lane >> 4, llo = lane & 15;
  const int bh = blockIdx.x;                 // bh%8 -> XCD; q-tiles of bh share L2
  const int q0 = (15 - blockIdx.y) << 7;     // heaviest q-tiles dispatch first
  const unsigned short* Qb = Qw  + (size_t)bh * 2048 * 64;
  const unsigned short* Kb = Kw  + (size_t)bh * 2048 * 64;
  const unsigned short* Vb = Vtw + (size_t)bh * 64 * 2048;

  const int qrow0 = q0 + wave * 16 + llo;    // qset0 query (column of S^T)
  bf16x8 qf[2][2];
  qf[0][0] = *(const bf16x8*)(Qb + (size_t)qrow0 * 64 + lhi * 8);
  qf[0][1] = *(const bf16x8*)(Qb + (size_t)qrow0 * 64 + 32 + lhi * 8);
  qf[1][0] = *(const bf16x8*)(Qb + (size_t)(qrow0 + 64) * 64 + lhi * 8);
  qf[1][1] = *(const bf16x8*)(Qb + (size_t)(qrow0 + 64) * 64 + 32 + lhi * 8);

  const int srow = t >> 3;
  const int scol = ((t & 7) ^ (srow & 7)) * 8;   // XOR-swizzled staging chunk
  const int cpos  = (lhi ^ (llo & 7)) * 8;       // swizzled chunk for frag reads
  const int cposx = cpos ^ 32;                   // chunk c^4

  float m_i[2] = {-1e30f, -1e30f}, l_i[2] = {0.f, 0.f};
  f32x4 o[2][4];
  f32x4 zero = {0.f, 0.f, 0.f, 0.f};
#pragma unroll
  for (int qs = 0; qs < 2; ++qs)
#pragma unroll
    for (int td = 0; td < 4; ++td) o[qs][td] = zero;

  const int kt_lo = (q0 > 511) ? ((q0 - 511) >> 6) : 0;
  const int kt_hi = (q0 + 64) >> 6;

  // prologue stage tile kt_lo into buf (kt_lo&1)
  {
    const int k0 = kt_lo << 6;
    unsigned short* dK = sK[kt_lo & 1];
    unsigned short* dV = sV[kt_lo & 1];
    gld16(Kb + (size_t)(k0 + srow) * 64 + scol,      dK + t * 8);
    gld16(Kb + (size_t)(k0 + srow + 32) * 64 + scol, dK + t * 8 + 2048);
    gld16(Vb + (size_t)srow * 2048 + k0 + scol,        dV + t * 8);
    gld16(Vb + (size_t)(srow + 32) * 2048 + k0 + scol, dV + t * 8 + 2048);
  }

  for (int kt = kt_lo; kt <= kt_hi; ++kt) {
    __syncthreads();   // staged buf[kt&1] ready; all reads of buf[(kt+1)&1] done
    if (kt < kt_hi) {  // prefetch next tile, overlapped with this tile's compute
      const int k0n = (kt + 1) << 6;
      unsigned short* dK = sK[(kt + 1) & 1];
      unsigned short* dV = sV[(kt + 1) & 1];
      gld16(Kb + (size_t)(k0n + srow) * 64 + scol,      dK + t * 8);
      gld16(Kb + (size_t)(k0n + srow + 32) * 64 + scol, dK + t * 8 + 2048);
      gld16(Vb + (size_t)srow * 2048 + k0n + scol,        dV + t * 8);
      gld16(Vb + (size_t)(srow + 32) * 2048 + k0n + scol, dV + t * 8 + 2048);
    }
    const unsigned short* bK = sK[kt & 1];
    const unsigned short* bV = sV[kt & 1];
    const int k0 = kt << 6;

#pragma unroll
    for (int qs = 0; qs < 2; ++qs) {
      const int qmin = q0 + qs * 64;
      if (k0 > qmin + 63 || k0 + 63 < qmin - (WINDOW - 1)) continue;  // block-uniform skip
      const int qrow = qrow0 + qs * 64;

      // S^T tiles: row = key (tk*16 + lhi*4 + r), col = query (llo)
      f32x4 st[4];
#pragma unroll
      for (int tk = 0; tk < 4; ++tk) {
        const unsigned short* kr = bK + (tk * 16 + llo) * 64;
        bf16x8 kf0 = *(const bf16x8*)(kr + cpos);
        bf16x8 kf1 = *(const bf16x8*)(kr + cposx);
        f32x4 z = zero;
        z = mfma16(kf0, qf[qs][0], z);
        z = mfma16(kf1, qf[qs][1], z);
        st[tk] = z;
      }

      // mask + in-lane max over 16 keys, then 2-shfl cross-quad reduce
      const int kb = k0 + lhi * 4;
      float mx = -1e30f;
#pragma unroll
      for (int tk = 0; tk < 4; ++tk)
#pragma unroll
        for (int r = 0; r < 4; ++r) {
          int key = kb + tk * 16 + r;
          bool ok = (key <= qrow) && (qrow - key < WINDOW);
          float s = ok ? st[tk][r] : -1e30f;
          st[tk][r] = s;
          mx = fmaxf(mx, s);
        }
      mx = fmaxf(mx, __shfl_xor(mx, 16));
      mx = fmaxf(mx, __shfl_xor(mx, 32));
      float mn = fmaxf(m_i[qs], mx);
      float a  = __expf(m_i[qs] - mn);  // garbage from fully-masked lanes wiped by a=0 later
      float rs = 0.f;
      unsigned short* pw = &sP[wave][llo * 72];
#pragma unroll
      for (int tk = 0; tk < 4; ++tk) {
        ushort4 pb;
        pb.x = f2bf(__expf(st[tk][0] - mn));
        pb.y = f2bf(__expf(st[tk][1] - mn));
        pb.z = f2bf(__expf(st[tk][2] - mn));
        pb.w = f2bf(__expf(st[tk][3] - mn));
        *(ushort4*)(pw + tk * 16 + lhi * 4) = pb;
        rs += bf2f(pb.x) + bf2f(pb.y) + bf2f(pb.z) + bf2f(pb.w);
      }
      rs += __shfl_xor(rs, 16);
      rs += __shfl_xor(rs, 32);
      l_i[qs] = l_i[qs] * a + rs;
      m_i[qs] = mn;

      float aR[4];
#pragma unroll
      for (int r = 0; r < 4; ++r) aR[r] = __shfl(a, lhi * 4 + r);
#pragma unroll
      for (int td = 0; td < 4; ++td)
#pragma unroll
        for (int r = 0; r < 4; ++r) o[qs][td][r] *= aR[r];

      // O += P V (same-wave LDS write->read, no barrier needed)
      bf16x8 pf0 = *(const bf16x8*)(pw + lhi * 8);
      bf16x8 pf1 = *(const bf16x8*)(pw + 32 + lhi * 8);
#pragma unroll
      for (int td = 0; td < 4; ++td) {
        const unsigned short* vr = bV + (td * 16 + llo) * 64;
        bf16x8 vf0 = *(const bf16x8*)(vr + cpos);
        bf16x8 vf1 = *(const bf16x8*)(vr + cposx);
        o[qs][td] = mfma16(pf0, vf0, o[qs][td]);
        o[qs][td] = mfma16(pf1, vf1, o[qs][td]);
      }
    }
  }

  const int b = bh >> 4, h = bh & 15;
#pragma unroll
  for (int qs = 0; qs < 2; ++qs) {
    float lR[4];
#pragma unroll
    for (int r = 0; r < 4; ++r) lR[r] = 1.f / __shfl(l_i[qs], lhi * 4 + r);
#pragma unroll
    for (int td = 0; td < 4; ++td)
#pragma unroll
      for (int r = 0; r < 4; ++r) {
        int qr = q0 + qs * 64 + wave * 16 + lhi * 4 + r;
        AO[(size_t)(b * 2048 + qr) * 1024 + h * 64 + td * 16 + llo] = f2bf(o[qs][td][r] * lR[r]);
      }
  }
}

// ---------------- output projection GEMM -------------------------------------------------
__global__ __launch_bounds__(256) void out_gemm_kernel(const unsigned short* __restrict__ AO,
                                                       const unsigned short* __restrict__ Wt,
                                                       const float* __restrict__ bias,
                                                       float* __restrict__ out) {
  __shared__ __align__(16) unsigned short sA[128 * 32];
  __shared__ __align__(16) unsigned short sB[128 * 32];
  f32x4 acc[4][4];
  const int m0 = blockIdx.y * 128, n0 = blockIdx.x * 128;
  gemm_mainloop<false>(AO, Wt, D_MODEL, m0, n0, sA, sB, acc);

  const int t = threadIdx.x, lane = t & 63, wave = t >> 6;
  const int wm = wave >> 1, wn = wave & 1, lhi = lane >> 4, llo = lane & 15;
#pragma unroll
  for (int ti = 0; ti < 4; ++ti)
#pragma unroll
    for (int tj = 0; tj < 4; ++tj) {
      int n = n0 + wn * 64 + tj * 16 + llo;
      float bv = bias[n];
#pragma unroll
      for (int r = 0; r < 4; ++r) {
        int m = m0 + wm * 64 + ti * 16 + lhi * 4 + r;
        out[(size_t)m * D_MODEL + n] = acc[ti][tj][r] + bv;
      }
    }
}

extern "C" void kernel_launch(void* const* d_in, const int* in_sizes, int n_in,
                              void* d_out, int out_size, void* d_ws, size_t ws_size,
                              hipStream_t stream) {
  const float* x      = (const float*)d_in[0];
  const float* qkv_w  = (const float*)d_in[1];
  const float* qkv_b  = (const float*)d_in[2];
  const float* out_w  = (const float*)d_in[3];
  const float* out_b  = (const float*)d_in[4];
  float* out = (float*)d_out;
  char* ws = (char*)d_ws;

  // workspace layout (48 MB total)
  unsigned short* Xb  = (unsigned short*)(ws);                          // 8 MB  x bf16
  unsigned short* Wq  = (unsigned short*)(ws + ((size_t)8  << 20));     // 6 MB  qkv_w^T bf16
  unsigned short* Wo  = (unsigned short*)(ws + ((size_t)14 << 20));     // 2 MB  out_w^T bf16
  unsigned short* Qw  = (unsigned short*)(ws + ((size_t)16 << 20));     // 8 MB  Q (bh,s,d)*1/8
  unsigned short* Kw  = (unsigned short*)(ws + ((size_t)24 << 20));     // 8 MB  K (bh,s,d)
  unsigned short* Vtw = (unsigned short*)(ws + ((size_t)32 << 20));     // 8 MB  V^T (bh,d,s)
  unsigned short* AO  = (unsigned short*)(ws + ((size_t)40 << 20));     // 8 MB  attn out (m,hd)

  cvt_bf16_kernel<<<MTOT * D_MODEL / 1024, 256, 0, stream>>>(x, Xb);
  transpose_cvt_kernel<<<dim3(NQKV / 32, D_MODEL / 32), dim3(32, 8), 0, stream>>>(qkv_w, Wq, D_MODEL, NQKV);
  transpose_cvt_kernel<<<dim3(D_MODEL / 32, D_MODEL / 32), dim3(32, 8), 0, stream>>>(out_w, Wo, D_MODEL, D_MODEL);
  qkv_gemm_kernel<<<dim3(NQKV / 128, MTOT / 128), 256, 0, stream>>>(Xb, Wq, qkv_b, Qw, Kw, Vtw);
  attn_kernel<<<dim3(BATCH * NUM_HEADS, SEQ / 128), 256, 0, stream>>>(Qw, Kw, Vtw, AO);
  out_gemm_kernel<<<dim3(D_MODEL / 128, MTOT / 128), 256, 0, stream>>>(AO, Wo, out_b, out);
}

// Round 4
// 172.499 us; speedup vs baseline: 1.1054x; 1.1054x over previous
//
#include <hip/hip_runtime.h>
#include <cstdint>
#include <cstddef>

#define NUM_HEADS 16
#define HEAD_DIM  64
#define WINDOW    512
#define D_MODEL   1024
#define BATCH     2
#define SEQ       2048
#define MTOT      (BATCH*SEQ)   // 4096
#define NQKV      (3*D_MODEL)   // 3072

typedef short bf16x8 __attribute__((ext_vector_type(8)));
typedef float f32x4  __attribute__((ext_vector_type(4)));

__device__ __forceinline__ f32x4 mfma16(bf16x8 a, bf16x8 b, f32x4 c) {
  return __builtin_amdgcn_mfma_f32_16x16x32_bf16(a, b, c, 0, 0, 0);
}

__device__ __forceinline__ unsigned short f2bf(float f) {
  unsigned int u = __float_as_uint(f);
  u += 0x7fffu + ((u >> 16) & 1u);
  return (unsigned short)(u >> 16);
}
__device__ __forceinline__ float bf2f(unsigned short b) {
  return __uint_as_float(((unsigned int)b) << 16);
}

// async global->LDS, 16B/lane; LDS dest = wave-uniform base + lane*16 (m104).
__device__ __forceinline__ void gld16(const unsigned short* g, unsigned short* l) {
  __builtin_amdgcn_global_load_lds(
      (const __attribute__((address_space(1))) unsigned int*)g,
      (__attribute__((address_space(3))) unsigned int*)l, 16, 0, 0);
}

// ---------------- fused prep: x->bf16 | qkv_w^T->bf16 | out_w^T->bf16 ----------------
// blocks [0,4096): cvt x; [4096,7168): transpose qkv_w; [7168,8192): transpose out_w.
__global__ __launch_bounds__(256) void prep_kernel(const float* __restrict__ x,
                                                   const float* __restrict__ qkv_w,
                                                   const float* __restrict__ out_w,
                                                   unsigned short* __restrict__ Xb,
                                                   unsigned short* __restrict__ Wq,
                                                   unsigned short* __restrict__ Wo) {
  __shared__ float tile[32][33];
  const int bid = blockIdx.x, t = threadIdx.x;
  if (bid < 4096) {
    int i = (bid * 256 + t) * 4;
    float4 v = *(const float4*)(x + i);
    ushort4 o;
    o.x = f2bf(v.x); o.y = f2bf(v.y); o.z = f2bf(v.z); o.w = f2bf(v.w);
    *(ushort4*)(Xb + i) = o;
    return;
  }
  const float* in; unsigned short* out; int R, C, bx, by;
  if (bid < 7168) { int b2 = bid - 4096; in = qkv_w; out = Wq; R = D_MODEL; C = NQKV; bx = b2 % 96; by = b2 / 96; }
  else            { int b2 = bid - 7168; in = out_w; out = Wo; R = D_MODEL; C = D_MODEL; bx = b2 & 31; by = b2 >> 5; }
  int tx = t & 31, ty = t >> 5;            // (32, 8)
  int c0 = bx * 32, r0 = by * 32;
#pragma unroll
  for (int i = 0; i < 32; i += 8)
    tile[ty + i][tx] = in[(size_t)(r0 + ty + i) * C + c0 + tx];
  __syncthreads();
#pragma unroll
  for (int i = 0; i < 32; i += 8)
    out[(size_t)(c0 + ty + i) * R + r0 + tx] = f2bf(tile[tx][ty + i]);
}

// ---------------- double-buffered bf16 GEMM mainloop, XOR-swizzled LDS -------------------
// A row-major (M,K), Bt row-major (N,K). Block tile: (TI*32) x 128, 4 waves in 2x2.
// SWAP=false: acc = C tile (row=m, col=n). SWAP=true: acc = C^T (row=n, col=m).
// One barrier per K-iter; prefetch of tile k+1 overlaps compute of tile k.
template<int TI, bool SWAP>
__device__ __forceinline__ void gemm_mainloop_db(const unsigned short* __restrict__ A,
                                                 const unsigned short* __restrict__ Bt,
                                                 int K, int m0, int n0,
                                                 unsigned short* sA0, unsigned short* sA1,
                                                 unsigned short* sB0, unsigned short* sB1,
                                                 f32x4 (&acc)[TI][4]) {
  const int t = threadIdx.x;
  const int lane = t & 63, wave = t >> 6;
  const int wm = wave >> 1, wn = wave & 1;
  const int lhi = lane >> 4, llo = lane & 15;
  f32x4 zero = {0.f, 0.f, 0.f, 0.f};
#pragma unroll
  for (int i = 0; i < TI; ++i)
#pragma unroll
    for (int j = 0; j < 4; ++j) acc[i][j] = zero;

  const int cswz = (((t & 3) ^ ((t >> 3) & 3)) << 3);   // swizzled k-chunk for staging
  const unsigned short* gA = A  + (size_t)(m0 + (t >> 2)) * K + cswz;
  const unsigned short* gB = Bt + (size_t)(n0 + (t >> 2)) * K + cswz;
  const size_t rowskip = (size_t)64 * K;
  const int ldsT = t * 8;
  const int rsw  = (lhi ^ ((llo >> 1) & 3)) * 8;        // swizzled chunk for frag reads
  const int aoff = (wm * (TI * 16) + llo) * 32 + rsw;
  const int boff = (wn * 64 + llo) * 32 + rsw;

  // prologue: stage tile 0 into buffer 0
  gld16(gA, sA0 + ldsT);
  if (TI == 4) gld16(gA + rowskip, sA0 + ldsT + 2048);
  gld16(gB, sB0 + ldsT);
  gld16(gB + rowskip, sB0 + ldsT + 2048);

  const int nIter = K >> 5;
  for (int it = 0; it < nIter; ++it) {
    __syncthreads();   // tile `it` resident; prior reads of the other buffer done
    unsigned short* cA = (it & 1) ? sA1 : sA0;
    unsigned short* cB = (it & 1) ? sB1 : sB0;
    if (it + 1 < nIter) {   // prefetch overlaps this tile's compute
      unsigned short* nA = (it & 1) ? sA0 : sA1;
      unsigned short* nB = (it & 1) ? sB0 : sB1;
      gA += 32; gB += 32;
      gld16(gA, nA + ldsT);
      if (TI == 4) gld16(gA + rowskip, nA + ldsT + 2048);
      gld16(gB, nB + ldsT);
      gld16(gB + rowskip, nB + ldsT + 2048);
    }
    bf16x8 af[TI], bfr[4];
#pragma unroll
    for (int i = 0; i < TI; ++i) af[i]  = *(const bf16x8*)(cA + aoff + i * 512);
#pragma unroll
    for (int j = 0; j < 4; ++j)  bfr[j] = *(const bf16x8*)(cB + boff + j * 512);
#pragma unroll
    for (int i = 0; i < TI; ++i)
#pragma unroll
      for (int j = 0; j < 4; ++j)
        acc[i][j] = SWAP ? mfma16(bfr[j], af[i], acc[i][j])
                         : mfma16(af[i], bfr[j], acc[i][j]);
  }
}

// ---------------- QKV projection GEMM -----------------------------------------------------
// n0 < 2048 blocks: Q/K, normal orientation, coalesced (bh,s,d) stores.
// n0 >= 2048 blocks: V, transposed accumulator, DIRECT V^T (bh,d,s) stores.
__global__ __launch_bounds__(256) void qkv_gemm_kernel(const unsigned short* __restrict__ Xb,
                                                       const unsigned short* __restrict__ Wt,
                                                       const float* __restrict__ bias,
                                                       unsigned short* __restrict__ Qw,
                                                       unsigned short* __restrict__ Kw,
                                                       unsigned short* __restrict__ Vtw) {
  __shared__ __align__(16) unsigned short sA[2][128 * 32];
  __shared__ __align__(16) unsigned short sB[2][128 * 32];
  f32x4 acc[4][4];
  const int m0 = blockIdx.y * 128, n0 = blockIdx.x * 128;
  const int t = threadIdx.x, lane = t & 63, wave = t >> 6;
  const int wm = wave >> 1, wn = wave & 1, lhi = lane >> 4, llo = lane & 15;

  if (n0 < 2048) {
    gemm_mainloop_db<4, false>(Xb, Wt, D_MODEL, m0, n0, sA[0], sA[1], sB[0], sB[1], acc);
#pragma unroll
    for (int ti = 0; ti < 4; ++ti) {
#pragma unroll
      for (int tj = 0; tj < 4; ++tj) {
        int n = n0 + wn * 64 + tj * 16 + llo;
        float bv = bias[n];
        int c = n >> 10, h = (n >> 6) & 15, d = n & 63;
#pragma unroll
        for (int r = 0; r < 4; ++r) {
          int m = m0 + wm * 64 + ti * 16 + lhi * 4 + r;
          int b = m >> 11, s = m & 2047;
          int bh = b * 16 + h;
          float v = acc[ti][tj][r] + bv;
          size_t idx = ((size_t)(bh * 2048 + s)) * 64 + d;
          if (c == 0) Qw[idx] = f2bf(v * 0.125f);
          else        Kw[idx] = f2bf(v);
        }
      }
    }
  } else {
    gemm_mainloop_db<4, true>(Xb, Wt, D_MODEL, m0, n0, sA[0], sA[1], sB[0], sB[1], acc);
#pragma unroll
    for (int ti = 0; ti < 4; ++ti) {
      int m = m0 + wm * 64 + ti * 16 + llo;   // s-dim (col of C^T)
      int b = m >> 11, s = m & 2047;
#pragma unroll
      for (int tj = 0; tj < 4; ++tj) {
        int nb = n0 + wn * 64 + tj * 16 + lhi * 4;   // d-base (row of C^T), 4-aligned
        float4 bv = *(const float4*)(bias + nb);
        int h = (nb >> 6) & 15, dbase = nb & 63;
        int bh = b * 16 + h;
        float bvr[4] = {bv.x, bv.y, bv.z, bv.w};
#pragma unroll
        for (int r = 0; r < 4; ++r)
          Vtw[(size_t)(bh * 64 + dbase + r) * 2048 + s] = f2bf(acc[ti][tj][r] + bvr[r]);
      }
    }
  }
}

// ---------------- flash sliding-window attention (S^T, 64-q tiles, dbuf K/V) -------------
// grid (bh, q-rev): 1024 blocks. One barrier per k-tile; prefetch overlaps softmax+MFMA.
__global__ __launch_bounds__(256) void attn_kernel(const unsigned short* __restrict__ Qw,
                                                   const unsigned short* __restrict__ Kw,
                                                   const unsigned short* __restrict__ Vtw,
                                                   unsigned short* __restrict__ AO) {
  __shared__ __align__(16) unsigned short sK[2][64 * 64];  // (key,d), XOR-swizzled chunks
  __shared__ __align__(16) unsigned short sV[2][64 * 64];  // (d,key), XOR-swizzled chunks
  __shared__ __align__(16) unsigned short sP[4][16 * 72];  // per-wave P (query,key), pad 72
  const int t = threadIdx.x, lane = t & 63, wave = t >> 6;
  const int lhi = lane >> 4, llo = lane & 15;
  const int bh = blockIdx.x;                 // bh%8 -> XCD; q-tiles of bh share L2
  const int q0 = (31 - blockIdx.y) << 6;     // heaviest q-tiles dispatch first
  const unsigned short* Qb = Qw  + (size_t)bh * 2048 * 64;
  const unsigned short* Kb = Kw  + (size_t)bh * 2048 * 64;
  const unsigned short* Vb = Vtw + (size_t)bh * 64 * 2048;

  const int qrow = q0 + wave * 16 + llo;     // this lane's query (column of S^T)
  bf16x8 qf0 = *(const bf16x8*)(Qb + (size_t)qrow * 64 + lhi * 8);
  bf16x8 qf1 = *(const bf16x8*)(Qb + (size_t)qrow * 64 + 32 + lhi * 8);

  const int srow = t >> 3;
  const int scol = ((t & 7) ^ (srow & 7)) * 8;   // XOR-swizzled staging chunk
  const int cpos  = (lhi ^ (llo & 7)) * 8;       // swizzled chunk for frag reads
  const int cposx = cpos ^ 32;                   // chunk c^4

  float m_i = -1e30f, l_i = 0.f;
  f32x4 o[4];
  f32x4 zero = {0.f, 0.f, 0.f, 0.f};
#pragma unroll
  for (int td = 0; td < 4; ++td) o[td] = zero;

  const int kt_lo = (q0 > 511) ? ((q0 - 511) >> 6) : 0;
  const int kt_hi = q0 >> 6;

  {  // prologue: stage tile kt_lo
    const int k0 = kt_lo << 6;
    unsigned short* dK = sK[kt_lo & 1];
    unsigned short* dV = sV[kt_lo & 1];
    gld16(Kb + (size_t)(k0 + srow) * 64 + scol,      dK + t * 8);
    gld16(Kb + (size_t)(k0 + srow + 32) * 64 + scol, dK + t * 8 + 2048);
    gld16(Vb + (size_t)srow * 2048 + k0 + scol,        dV + t * 8);
    gld16(Vb + (size_t)(srow + 32) * 2048 + k0 + scol, dV + t * 8 + 2048);
  }

  for (int kt = kt_lo; kt <= kt_hi; ++kt) {
    __syncthreads();   // staged buf[kt&1] ready; prior reads of the other buffer done
    if (kt < kt_hi) {  // prefetch next tile, overlapped with this tile's compute
      const int k0n = (kt + 1) << 6;
      unsigned short* dK = sK[(kt + 1) & 1];
      unsigned short* dV = sV[(kt + 1) & 1];
      gld16(Kb + (size_t)(k0n + srow) * 64 + scol,      dK + t * 8);
      gld16(Kb + (size_t)(k0n + srow + 32) * 64 + scol, dK + t * 8 + 2048);
      gld16(Vb + (size_t)srow * 2048 + k0n + scol,        dV + t * 8);
      gld16(Vb + (size_t)(srow + 32) * 2048 + k0n + scol, dV + t * 8 + 2048);
    }
    const unsigned short* bK = sK[kt & 1];
    const unsigned short* bV = sV[kt & 1];
    const int k0 = kt << 6;

    // S^T tiles: row = key (tk*16 + lhi*4 + r), col = query (llo)
    f32x4 st[4];
#pragma unroll
    for (int tk = 0; tk < 4; ++tk) {
      const unsigned short* kr = bK + (tk * 16 + llo) * 64;
      bf16x8 kf0 = *(const bf16x8*)(kr + cpos);
      bf16x8 kf1 = *(const bf16x8*)(kr + cposx);
      f32x4 z = zero;
      z = mfma16(kf0, qf0, z);
      z = mfma16(kf1, qf1, z);
      st[tk] = z;
    }

    // mask + in-lane max over 16 keys, then 2-shfl cross-quad reduce
    const int kb = k0 + lhi * 4;
    float mx = -1e30f;
#pragma unroll
    for (int tk = 0; tk < 4; ++tk)
#pragma unroll
      for (int r = 0; r < 4; ++r) {
        int key = kb + tk * 16 + r;
        bool ok = (key <= qrow) && (qrow - key < WINDOW);
        float s = ok ? st[tk][r] : -1e30f;
        st[tk][r] = s;
        mx = fmaxf(mx, s);
      }
    mx = fmaxf(mx, __shfl_xor(mx, 16));
    mx = fmaxf(mx, __shfl_xor(mx, 32));
    float mn = fmaxf(m_i, mx);
    float a  = __expf(m_i - mn);
    float rs = 0.f;
    unsigned short* pw = &sP[wave][llo * 72];
#pragma unroll
    for (int tk = 0; tk < 4; ++tk) {
      ushort4 pb;
      pb.x = f2bf(__expf(st[tk][0] - mn));
      pb.y = f2bf(__expf(st[tk][1] - mn));
      pb.z = f2bf(__expf(st[tk][2] - mn));
      pb.w = f2bf(__expf(st[tk][3] - mn));
      *(ushort4*)(pw + tk * 16 + lhi * 4) = pb;
      rs += bf2f(pb.x) + bf2f(pb.y) + bf2f(pb.z) + bf2f(pb.w);
    }
    rs += __shfl_xor(rs, 16);
    rs += __shfl_xor(rs, 32);
    l_i = l_i * a + rs;
    m_i = mn;

    float aR[4];
#pragma unroll
    for (int r = 0; r < 4; ++r) aR[r] = __shfl(a, lhi * 4 + r);
#pragma unroll
    for (int td = 0; td < 4; ++td)
#pragma unroll
      for (int r = 0; r < 4; ++r) o[td][r] *= aR[r];

    // O += P V (same-wave LDS write->read ordering, no barrier needed)
    bf16x8 pf0 = *(const bf16x8*)(pw + lhi * 8);
    bf16x8 pf1 = *(const bf16x8*)(pw + 32 + lhi * 8);
#pragma unroll
    for (int td = 0; td < 4; ++td) {
      const unsigned short* vr = bV + (td * 16 + llo) * 64;
      bf16x8 vf0 = *(const bf16x8*)(vr + cpos);
      bf16x8 vf1 = *(const bf16x8*)(vr + cposx);
      o[td] = mfma16(pf0, vf0, o[td]);
      o[td] = mfma16(pf1, vf1, o[td]);
    }
  }

  float lR[4];
#pragma unroll
  for (int r = 0; r < 4; ++r) lR[r] = 1.f / __shfl(l_i, lhi * 4 + r);
  const int b = bh >> 4, h = bh & 15;
#pragma unroll
  for (int td = 0; td < 4; ++td)
#pragma unroll
    for (int r = 0; r < 4; ++r) {
      int qr = q0 + wave * 16 + lhi * 4 + r;
      AO[(size_t)(b * 2048 + qr) * 1024 + h * 64 + td * 16 + llo] = f2bf(o[td][r] * lR[r]);
    }
}

// ---------------- output projection GEMM (64x128 tile -> 512 blocks) ---------------------
__global__ __launch_bounds__(256) void out_gemm_kernel(const unsigned short* __restrict__ AO,
                                                       const unsigned short* __restrict__ Wt,
                                                       const float* __restrict__ bias,
                                                       float* __restrict__ out) {
  __shared__ __align__(16) unsigned short sA[2][64 * 32];
  __shared__ __align__(16) unsigned short sB[2][128 * 32];
  f32x4 acc[2][4];
  const int m0 = blockIdx.y * 64, n0 = blockIdx.x * 128;
  gemm_mainloop_db<2, false>(AO, Wt, D_MODEL, m0, n0, sA[0], sA[1], sB[0], sB[1], acc);

  const int t = threadIdx.x, lane = t & 63, wave = t >> 6;
  const int wm = wave >> 1, wn = wave & 1, lhi = lane >> 4, llo = lane & 15;
#pragma unroll
  for (int ti = 0; ti < 2; ++ti)
#pragma unroll
    for (int tj = 0; tj < 4; ++tj) {
      int n = n0 + wn * 64 + tj * 16 + llo;
      float bv = bias[n];
#pragma unroll
      for (int r = 0; r < 4; ++r) {
        int m = m0 + wm * 32 + ti * 16 + lhi * 4 + r;
        out[(size_t)m * D_MODEL + n] = acc[ti][tj][r] + bv;
      }
    }
}

extern "C" void kernel_launch(void* const* d_in, const int* in_sizes, int n_in,
                              void* d_out, int out_size, void* d_ws, size_t ws_size,
                              hipStream_t stream) {
  const float* x      = (const float*)d_in[0];
  const float* qkv_w  = (const float*)d_in[1];
  const float* qkv_b  = (const float*)d_in[2];
  const float* out_w  = (const float*)d_in[3];
  const float* out_b  = (const float*)d_in[4];
  float* out = (float*)d_out;
  char* ws = (char*)d_ws;

  // workspace layout (48 MB total)
  unsigned short* Xb  = (unsigned short*)(ws);                          // 8 MB  x bf16
  unsigned short* Wq  = (unsigned short*)(ws + ((size_t)8  << 20));     // 6 MB  qkv_w^T bf16
  unsigned short* Wo  = (unsigned short*)(ws + ((size_t)14 << 20));     // 2 MB  out_w^T bf16
  unsigned short* Qw  = (unsigned short*)(ws + ((size_t)16 << 20));     // 8 MB  Q (bh,s,d)*1/8
  unsigned short* Kw  = (unsigned short*)(ws + ((size_t)24 << 20));     // 8 MB  K (bh,s,d)
  unsigned short* Vtw = (unsigned short*)(ws + ((size_t)32 << 20));     // 8 MB  V^T (bh,d,s)
  unsigned short* AO  = (unsigned short*)(ws + ((size_t)40 << 20));     // 8 MB  attn out (m,hd)

  prep_kernel<<<8192, 256, 0, stream>>>(x, qkv_w, out_w, Xb, Wq, Wo);
  qkv_gemm_kernel<<<dim3(NQKV / 128, MTOT / 128), 256, 0, stream>>>(Xb, Wq, qkv_b, Qw, Kw, Vtw);
  attn_kernel<<<dim3(BATCH * NUM_HEADS, SEQ / 64), 256, 0, stream>>>(Qw, Kw, Vtw, AO);
  out_gemm_kernel<<<dim3(D_MODEL / 128, MTOT / 64), 256, 0, stream>>>(AO, Wo, out_b, out);
}